// Round 5
// baseline (868.970 us; speedup 1.0000x reference)
//
#include <hip/hip_runtime.h>
#include <math.h>
#include <string.h>

#define TSTEPS 40
#define BTOT   16384
#define HDIM   128
#define BT     32            // batch rows per block -> grid 512 = 2 blocks/CU
#define ZSTR   168           // zbuf row stride in shorts (160 cols + pad; 2-way-free banks)
#define NWAVE  8

typedef __attribute__((ext_vector_type(8))) short bf16x8;
typedef __attribute__((ext_vector_type(4))) float f32x4;

__device__ __forceinline__ short f2bf(float f) {
    unsigned int u; memcpy(&u, &f, 4);
    u += 0x7fffu + ((u >> 16) & 1u);
    return (short)(u >> 16);
}
__device__ __forceinline__ float bf2f(short s) {
    unsigned int u = ((unsigned int)(unsigned short)s) << 16;
    float f; memcpy(&f, &u, 4);
    return f;
}
__device__ __forceinline__ void gload_lds16(const float* g, void* lds) {
    __builtin_amdgcn_global_load_lds(
        (const __attribute__((address_space(1))) void*)g,
        (__attribute__((address_space(3))) void*)lds, 16, 0, 0);
}

__global__ __launch_bounds__(512, 4)
void lsnn5(const float* __restrict__ x,
           const float* __restrict__ w_in,
           const float* __restrict__ w_rec,
           const float* __restrict__ w_out,
           const float* __restrict__ dm,
           float* __restrict__ out)
{
    __shared__ short zbuf[2][BT][ZSTR];      // cols 0..127 = z_{t-1}; 128..135 = x_t; 136.. = 0
    __shared__ float dmb[2][BT * HDIM];      // dropout mask slice, double-buffered
    __shared__ float red[2][NWAVE][BT][2];   // readout partials, double-buffered

    const int tid   = threadIdx.x;
    const int l     = tid & 63;
    const int wv    = tid >> 6;
    const int li    = l & 15;
    const int q     = l >> 4;
    const int bbase = blockIdx.x * BT;
    const int hcol  = wv * 16 + li;

    // ---- register-resident B fragments: [w_rec | w_in] 3-way bf16 split ----
    bf16x8 wB[5][3];
    #pragma unroll
    for (int kt = 0; kt < 4; ++kt) {
        const float* src = w_rec + hcol * HDIM + kt * 32 + q * 8;
        #pragma unroll
        for (int i = 0; i < 8; ++i) {
            float w0 = src[i];
            short h0 = f2bf(w0); float r1 = w0 - bf2f(h0);
            short h1 = f2bf(r1); float r2 = r1 - bf2f(h1);
            wB[kt][0][i] = h0; wB[kt][1][i] = h1; wB[kt][2][i] = f2bf(r2);
        }
    }
    #pragma unroll
    for (int i = 0; i < 8; ++i) { wB[4][0][i] = 0; wB[4][1][i] = 0; wB[4][2][i] = 0; }
    if (q == 0) {
        const float* src = w_in + hcol * 8;
        #pragma unroll
        for (int i = 0; i < 8; ++i) {
            float w0 = src[i];
            short h0 = f2bf(w0); float r1 = w0 - bf2f(h0);
            short h1 = f2bf(r1); float r2 = r1 - bf2f(h1);
            wB[4][0][i] = h0; wB[4][1][i] = h1; wB[4][2][i] = f2bf(r2);
        }
    }
    const float wo0 = w_out[hcol];
    const float wo1 = w_out[HDIM + hcol];

    // ---- LSNN state (C-fragment layout: row = rt*16 + q*4 + r) ----
    f32x4 v[2], cu[2], ba[2];
    #pragma unroll
    for (int rt = 0; rt < 2; ++rt) {
        v[rt]  = (f32x4){0.f,0.f,0.f,0.f};
        cu[rt] = (f32x4){0.f,0.f,0.f,0.f};
        ba[rt] = (f32x4){0.f,0.f,0.f,0.f};
    }

    // ---- encoder (tid<256): row = tid>>3, ch = tid&7, feature = tid&3 ----
    float ve = 0.f, ce = 0.f;
    if (tid < 256) {
        float xv = 50.f * x[(bbase + (tid >> 3)) * 4 + (tid & 3)];
        ce = ((tid & 7) < 4) ? fmaxf(xv, 0.f) : fmaxf(-xv, 0.f);
    }

    // ---- LI readout state (wave 0: lane l <-> (row=l>>1, o=l&1)) ----
    float vo = 0.f, io = 0.f, mx = 0.f;

    const float KA = 1.4285714285714286e-06f;  // DT * (1/700)
    const float KB = 2.5714285714285714e-03f;  // (1/700) * 1.8

    // zero zbuf (both parities; cols >=136 stay 0 forever) and red[0]
    for (int idx = tid; idx < 2 * BT * ZSTR; idx += 512) ((short*)zbuf)[idx] = 0;
    for (int idx = tid; idx < NWAVE * BT * 2; idx += 512) ((float*)red)[idx] = 0.f;
    __syncthreads();

    // prologue: x_0 spikes -> zbuf[0]; dm slice t=0 -> dmb[0]
    if (tid < 256) {
        float vv = ve + 0.1f * (ce - ve);
        float sp = (vv - 1.0f > 0.f) ? 1.f : 0.f;
        ve = (1.f - sp) * vv;
        zbuf[0][tid >> 3][128 + (tid & 7)] = (sp > 0.5f) ? (short)0x3F80 : (short)0;
    }
    {
        const float* g = dm + (size_t)bbase * HDIM;
        char* lb = (char*)&dmb[0][0];
        gload_lds16(g + tid * 4, lb + tid * 16);
        gload_lds16(g + 2048 + tid * 4, lb + 8192 + tid * 16);
    }

    for (int t = 0; t < TSTEPS; ++t) {
        const int p = t & 1;
        __syncthreads();   // zbuf[p]/dmb[p]/red[p] ready; [1-p] buffers free

        // 1) dm prefetch for t+1 -> dmb[1-p] (drains at next step's barrier)
        {
            int tn = (t + 1 < TSTEPS) ? t + 1 : TSTEPS - 1;
            const float* g = dm + ((size_t)tn * BTOT + bbase) * HDIM;
            char* lb = (char*)&dmb[1 - p][0];
            gload_lds16(g + tid * 4, lb + tid * 16);
            gload_lds16(g + 2048 + tid * 4, lb + 8192 + tid * 16);
        }

        // 2) LI readout for tau = t-1 (wave 0; red[0] zeros make t=0 a no-op)
        if (wv == 0) {
            int row = l >> 1, o = l & 1;
            float s = 0.f;
            #pragma unroll
            for (int w = 0; w < NWAVE; ++w) s += red[p][w][row][o];
            float von = vo + 0.1f * (io - vo);
            io = io - 0.2f * io + s;
            vo = von;
            mx = fmaxf(mx, vo);
        }

        // 3) encoder spike for t+1 -> zbuf[1-p] cols 128..135
        if (tid < 256) {
            float vv = ve + 0.1f * (ce - ve);
            float sp = (vv - 1.0f > 0.f) ? 1.f : 0.f;
            ve = (1.f - sp) * vv;
            zbuf[1 - p][tid >> 3][128 + (tid & 7)] = (sp > 0.5f) ? (short)0x3F80 : (short)0;
        }

        // 4) MFMA: acc[rt] = [z_{t-1} | x_t] @ [w_rec | w_in]^T  (K = 160)
        f32x4 acc[2];
        #pragma unroll
        for (int rt = 0; rt < 2; ++rt) {
            f32x4 a = {0.f, 0.f, 0.f, 0.f};
            #pragma unroll
            for (int kt = 0; kt < 5; ++kt) {
                bf16x8 zA = *reinterpret_cast<const bf16x8*>(&zbuf[p][rt * 16 + li][kt * 32 + q * 8]);
                #pragma unroll
                for (int pp = 0; pp < 3; ++pp)
                    a = __builtin_amdgcn_mfma_f32_16x16x32_bf16(zA, wB[kt][pp], a, 0, 0, 0);
            }
            acc[rt] = a;
        }

        // 5) elementwise cell + z publish + readout partial reduce -> red[1-p]
        #pragma unroll
        for (int rt = 0; rt < 2; ++rt) {
            float p0r[4], p1r[4];
            #pragma unroll
            for (int r = 0; r < 4; ++r) {
                int row = rt * 16 + q * 4 + r;
                float vd = v[rt][r] + 0.1f * (cu[rt][r] - v[rt][r]);
                float id = cu[rt][r] - 0.2f * cu[rt][r];
                float bd = ba[rt][r] + KA * (1.0f - ba[rt][r]);
                float z  = (vd - bd > 0.f) ? 1.f : 0.f;
                v[rt][r]  = (1.f - z) * vd;
                ba[rt][r] = bd + z * KB;
                cu[rt][r] = id + acc[rt][r];
                zbuf[1 - p][row][hcol] = (z > 0.5f) ? (short)0x3F80 : (short)0;
                float zd = z * dmb[p][row * HDIM + hcol];
                p0r[r] = zd * wo0;
                p1r[r] = zd * wo1;
            }
            #pragma unroll
            for (int s = 1; s < 16; s <<= 1) {
                #pragma unroll
                for (int r = 0; r < 4; ++r) {
                    p0r[r] += __shfl_xor(p0r[r], s);
                    p1r[r] += __shfl_xor(p1r[r], s);
                }
            }
            if (li == 0) {
                #pragma unroll
                for (int r = 0; r < 4; ++r) {
                    red[1 - p][wv][rt * 16 + q * 4 + r][0] = p0r[r];
                    red[1 - p][wv][rt * 16 + q * 4 + r][1] = p1r[r];
                }
            }
        }
    }

    // drain tau = TSTEPS-1 (its partials sit in red[TSTEPS & 1] = red[0]), then softmax
    __syncthreads();
    if (wv == 0) {
        int row = l >> 1, o = l & 1;
        float s = 0.f;
        #pragma unroll
        for (int w = 0; w < NWAVE; ++w) s += red[TSTEPS & 1][w][row][o];
        float von = vo + 0.1f * (io - vo);
        vo = von;
        mx = fmaxf(mx, vo);
        float other = __shfl_xor(mx, 1);
        float mmax  = fmaxf(mx, other);
        float e  = expf(mx - mmax);
        float eo = expf(other - mmax);
        out[(size_t)(bbase + row) * 2 + o] = e / (e + eo);
    }
}

extern "C" void kernel_launch(void* const* d_in, const int* in_sizes, int n_in,
                              void* d_out, int out_size, void* d_ws, size_t ws_size,
                              hipStream_t stream) {
    const float* x     = (const float*)d_in[0];
    const float* w_in  = (const float*)d_in[1];
    const float* w_rec = (const float*)d_in[2];
    const float* w_out = (const float*)d_in[3];
    const float* dmask = (const float*)d_in[4];
    float* outp = (float*)d_out;

    lsnn5<<<BTOT / BT, 512, 0, stream>>>(x, w_in, w_rec, w_out, dmask, outp);
}

// Round 6
// 560.146 us; speedup vs baseline: 1.5513x; 1.5513x over previous
//
#include <hip/hip_runtime.h>
#include <math.h>
#include <string.h>

#define TSTEPS 40
#define BTOT   16384
#define HDIM   128
#define BT     32            // batch rows per block -> grid 512 = 2 blocks/CU
#define ZSTR   168           // zbuf row stride in shorts (160 cols + pad; 2-way-free banks)
#define NWAVE  8

typedef __attribute__((ext_vector_type(8))) short bf16x8;
typedef __attribute__((ext_vector_type(4))) float f32x4;

__device__ __forceinline__ short f2bf(float f) {
    unsigned int u; memcpy(&u, &f, 4);
    u += 0x7fffu + ((u >> 16) & 1u);
    return (short)(u >> 16);
}
__device__ __forceinline__ float bf2f(short s) {
    unsigned int u = ((unsigned int)(unsigned short)s) << 16;
    float f; memcpy(&f, &u, 4);
    return f;
}
__device__ __forceinline__ void gload_lds16(const float* g, void* lds) {
    __builtin_amdgcn_global_load_lds(
        (const __attribute__((address_space(1))) void*)g,
        (__attribute__((address_space(3))) void*)lds, 16, 0, 0);
}

// launch_bounds(512, 2): observed gfx950 behavior treats arg2 as min BLOCKS/CU
// (R5: arg=4 -> 64-VGPR clamp -> 254MB spill). 2 blocks/CU -> 128-VGPR budget,
// which fits this kernel's natural ~108-VGPR footprint (R4 evidence).
__global__ __launch_bounds__(512, 2)
void lsnn6(const float* __restrict__ x,
           const float* __restrict__ w_in,
           const float* __restrict__ w_rec,
           const float* __restrict__ w_out,
           const float* __restrict__ dm,
           float* __restrict__ out)
{
    __shared__ short zbuf[2][BT][ZSTR];      // cols 0..127 = z_{t-1}; 128..135 = x_t; 136.. = 0
    __shared__ float dmb[2][BT * HDIM];      // dropout mask slice, double-buffered
    __shared__ float red[2][NWAVE][BT][2];   // readout partials, double-buffered

    const int tid   = threadIdx.x;
    const int l     = tid & 63;
    const int wv    = tid >> 6;
    const int li    = l & 15;
    const int q     = l >> 4;
    const int bbase = blockIdx.x * BT;
    const int hcol  = wv * 16 + li;

    // ---- register-resident B fragments: [w_rec | w_in] 3-way bf16 split ----
    bf16x8 wB[5][3];
    #pragma unroll
    for (int kt = 0; kt < 4; ++kt) {
        const float* src = w_rec + hcol * HDIM + kt * 32 + q * 8;
        #pragma unroll
        for (int i = 0; i < 8; ++i) {
            float w0 = src[i];
            short h0 = f2bf(w0); float r1 = w0 - bf2f(h0);
            short h1 = f2bf(r1); float r2 = r1 - bf2f(h1);
            wB[kt][0][i] = h0; wB[kt][1][i] = h1; wB[kt][2][i] = f2bf(r2);
        }
    }
    #pragma unroll
    for (int i = 0; i < 8; ++i) { wB[4][0][i] = 0; wB[4][1][i] = 0; wB[4][2][i] = 0; }
    if (q == 0) {
        const float* src = w_in + hcol * 8;
        #pragma unroll
        for (int i = 0; i < 8; ++i) {
            float w0 = src[i];
            short h0 = f2bf(w0); float r1 = w0 - bf2f(h0);
            short h1 = f2bf(r1); float r2 = r1 - bf2f(h1);
            wB[4][0][i] = h0; wB[4][1][i] = h1; wB[4][2][i] = f2bf(r2);
        }
    }
    const float wo0 = w_out[hcol];
    const float wo1 = w_out[HDIM + hcol];

    // ---- LSNN state (C-fragment layout: row = rt*16 + q*4 + r) ----
    f32x4 v[2], cu[2], ba[2];
    #pragma unroll
    for (int rt = 0; rt < 2; ++rt) {
        v[rt]  = (f32x4){0.f,0.f,0.f,0.f};
        cu[rt] = (f32x4){0.f,0.f,0.f,0.f};
        ba[rt] = (f32x4){0.f,0.f,0.f,0.f};
    }

    // ---- encoder (tid<256): row = tid>>3, ch = tid&7, feature = tid&3 ----
    float ve = 0.f, ce = 0.f;
    if (tid < 256) {
        float xv = 50.f * x[(bbase + (tid >> 3)) * 4 + (tid & 3)];
        ce = ((tid & 7) < 4) ? fmaxf(xv, 0.f) : fmaxf(-xv, 0.f);
    }

    // ---- LI readout state (wave 0: lane l <-> (row=l>>1, o=l&1)) ----
    float vo = 0.f, io = 0.f, mx = 0.f;

    const float KA = 1.4285714285714286e-06f;  // DT * (1/700)
    const float KB = 2.5714285714285714e-03f;  // (1/700) * 1.8

    // zero zbuf (both parities; cols >=136 stay 0 forever) and red[0]
    for (int idx = tid; idx < 2 * BT * ZSTR; idx += 512) ((short*)zbuf)[idx] = 0;
    for (int idx = tid; idx < NWAVE * BT * 2; idx += 512) ((float*)red)[idx] = 0.f;
    __syncthreads();

    // prologue: x_0 spikes -> zbuf[0]; dm slice t=0 -> dmb[0]
    if (tid < 256) {
        float vv = ve + 0.1f * (ce - ve);
        float sp = (vv - 1.0f > 0.f) ? 1.f : 0.f;
        ve = (1.f - sp) * vv;
        zbuf[0][tid >> 3][128 + (tid & 7)] = (sp > 0.5f) ? (short)0x3F80 : (short)0;
    }
    {
        const float* g = dm + (size_t)bbase * HDIM;
        char* lb = (char*)&dmb[0][0];
        gload_lds16(g + tid * 4, lb + tid * 16);
        gload_lds16(g + 2048 + tid * 4, lb + 8192 + tid * 16);
    }

    for (int t = 0; t < TSTEPS; ++t) {
        const int p = t & 1;
        __syncthreads();   // zbuf[p]/dmb[p]/red[p] ready; [1-p] buffers free

        // 1) dm prefetch for t+1 -> dmb[1-p] (drains at next step's barrier)
        {
            int tn = (t + 1 < TSTEPS) ? t + 1 : TSTEPS - 1;
            const float* g = dm + ((size_t)tn * BTOT + bbase) * HDIM;
            char* lb = (char*)&dmb[1 - p][0];
            gload_lds16(g + tid * 4, lb + tid * 16);
            gload_lds16(g + 2048 + tid * 4, lb + 8192 + tid * 16);
        }

        // 2) LI readout for tau = t-1 (wave 0; red[0] zeros make t=0 a no-op)
        if (wv == 0) {
            int row = l >> 1, o = l & 1;
            float s = 0.f;
            #pragma unroll
            for (int w = 0; w < NWAVE; ++w) s += red[p][w][row][o];
            float von = vo + 0.1f * (io - vo);
            io = io - 0.2f * io + s;
            vo = von;
            mx = fmaxf(mx, vo);
        }

        // 3) encoder spike for t+1 -> zbuf[1-p] cols 128..135
        if (tid < 256) {
            float vv = ve + 0.1f * (ce - ve);
            float sp = (vv - 1.0f > 0.f) ? 1.f : 0.f;
            ve = (1.f - sp) * vv;
            zbuf[1 - p][tid >> 3][128 + (tid & 7)] = (sp > 0.5f) ? (short)0x3F80 : (short)0;
        }

        // 4) MFMA: acc[rt] = [z_{t-1} | x_t] @ [w_rec | w_in]^T  (K = 160)
        f32x4 acc[2];
        #pragma unroll
        for (int rt = 0; rt < 2; ++rt) {
            f32x4 a = {0.f, 0.f, 0.f, 0.f};
            #pragma unroll
            for (int kt = 0; kt < 5; ++kt) {
                bf16x8 zA = *reinterpret_cast<const bf16x8*>(&zbuf[p][rt * 16 + li][kt * 32 + q * 8]);
                #pragma unroll
                for (int pp = 0; pp < 3; ++pp)
                    a = __builtin_amdgcn_mfma_f32_16x16x32_bf16(zA, wB[kt][pp], a, 0, 0, 0);
            }
            acc[rt] = a;
        }

        // 5) elementwise cell + z publish + readout partial reduce -> red[1-p]
        #pragma unroll
        for (int rt = 0; rt < 2; ++rt) {
            float p0r[4], p1r[4];
            #pragma unroll
            for (int r = 0; r < 4; ++r) {
                int row = rt * 16 + q * 4 + r;
                float vd = v[rt][r] + 0.1f * (cu[rt][r] - v[rt][r]);
                float id = cu[rt][r] - 0.2f * cu[rt][r];
                float bd = ba[rt][r] + KA * (1.0f - ba[rt][r]);
                float z  = (vd - bd > 0.f) ? 1.f : 0.f;
                v[rt][r]  = (1.f - z) * vd;
                ba[rt][r] = bd + z * KB;
                cu[rt][r] = id + acc[rt][r];
                zbuf[1 - p][row][hcol] = (z > 0.5f) ? (short)0x3F80 : (short)0;
                float zd = z * dmb[p][row * HDIM + hcol];
                p0r[r] = zd * wo0;
                p1r[r] = zd * wo1;
            }
            #pragma unroll
            for (int s = 1; s < 16; s <<= 1) {
                #pragma unroll
                for (int r = 0; r < 4; ++r) {
                    p0r[r] += __shfl_xor(p0r[r], s);
                    p1r[r] += __shfl_xor(p1r[r], s);
                }
            }
            if (li == 0) {
                #pragma unroll
                for (int r = 0; r < 4; ++r) {
                    red[1 - p][wv][rt * 16 + q * 4 + r][0] = p0r[r];
                    red[1 - p][wv][rt * 16 + q * 4 + r][1] = p1r[r];
                }
            }
        }
    }

    // drain tau = TSTEPS-1 (its partials sit in red[TSTEPS & 1] = red[0]), then softmax
    __syncthreads();
    if (wv == 0) {
        int row = l >> 1, o = l & 1;
        float s = 0.f;
        #pragma unroll
        for (int w = 0; w < NWAVE; ++w) s += red[TSTEPS & 1][w][row][o];
        float von = vo + 0.1f * (io - vo);
        vo = von;
        mx = fmaxf(mx, vo);
        float other = __shfl_xor(mx, 1);
        float mmax  = fmaxf(mx, other);
        float e  = expf(mx - mmax);
        float eo = expf(other - mmax);
        out[(size_t)(bbase + row) * 2 + o] = e / (e + eo);
    }
}

extern "C" void kernel_launch(void* const* d_in, const int* in_sizes, int n_in,
                              void* d_out, int out_size, void* d_ws, size_t ws_size,
                              hipStream_t stream) {
    const float* x     = (const float*)d_in[0];
    const float* w_in  = (const float*)d_in[1];
    const float* w_rec = (const float*)d_in[2];
    const float* w_out = (const float*)d_in[3];
    const float* dmask = (const float*)d_in[4];
    float* outp = (float*)d_out;

    lsnn6<<<BTOT / BT, 512, 0, stream>>>(x, w_in, w_rec, w_out, dmask, outp);
}

// Round 7
// 460.230 us; speedup vs baseline: 1.8881x; 1.2171x over previous
//
#include <hip/hip_runtime.h>
#include <math.h>
#include <string.h>

#define TSTEPS 40
#define BTOT   16384
#define HDIM   128
#define BT     32            // batch rows per block -> grid 512
#define ZSTR   168           // zbuf row stride in shorts (16B-aligned rows)
#define NWAVE  8

typedef __attribute__((ext_vector_type(8))) short bf16x8;
typedef __attribute__((ext_vector_type(4))) float f32x4;
typedef __attribute__((ext_vector_type(4))) unsigned int u32x4;

__device__ __forceinline__ short f2bf(float f) {
    unsigned int u; memcpy(&u, &f, 4);
    u += 0x7fffu + ((u >> 16) & 1u);
    return (short)(u >> 16);
}
__device__ __forceinline__ float bf2f(short s) {
    unsigned int u = ((unsigned int)(unsigned short)s) << 16;
    float f; memcpy(&f, &u, 4);
    return f;
}

// launch_bounds arg2 = min BLOCKS/CU on gfx950 (R5: 4 -> 64-VGPR clamp+spill;
// R6: 2 -> natural 84). 2 blocks/CU => 128-VGPR budget.
__global__ __launch_bounds__(512, 2)
void lsnn7(const float* __restrict__ x,
           const float* __restrict__ w_in,
           const float* __restrict__ w_rec,
           const float* __restrict__ w_out,
           const float* __restrict__ dm,
           float* __restrict__ out)
{
    __shared__ short zbuf[2][BT][ZSTR];               // cols 0..127 z, 128..135 x_t, 136.. = 0
    __shared__ unsigned short maskb[TSTEPS][BT][NWAVE]; // spike&keep bitmask chunks (20 KB)
    __shared__ float sbuf[TSTEPS][BT][2];             // readout drives s[t][row][o] (10 KB)

    const int tid   = threadIdx.x;
    const int l     = tid & 63;
    const int wv    = tid >> 6;
    const int li    = l & 15;
    const int q     = l >> 4;
    const int bbase = blockIdx.x * BT;
    const int hcol  = wv * 16 + li;

    // ---- register-resident B fragments: [w_rec | w_in] 3-way bf16 split ----
    bf16x8 wB[5][3];
    #pragma unroll
    for (int kt = 0; kt < 4; ++kt) {
        const float* src = w_rec + hcol * HDIM + kt * 32 + q * 8;
        #pragma unroll
        for (int i = 0; i < 8; ++i) {
            float w0 = src[i];
            short h0 = f2bf(w0); float r1 = w0 - bf2f(h0);
            short h1 = f2bf(r1); float r2 = r1 - bf2f(h1);
            wB[kt][0][i] = h0; wB[kt][1][i] = h1; wB[kt][2][i] = f2bf(r2);
        }
    }
    #pragma unroll
    for (int i = 0; i < 8; ++i) { wB[4][0][i] = 0; wB[4][1][i] = 0; wB[4][2][i] = 0; }
    if (q == 0) {
        const float* src = w_in + hcol * 8;
        #pragma unroll
        for (int i = 0; i < 8; ++i) {
            float w0 = src[i];
            short h0 = f2bf(w0); float r1 = w0 - bf2f(h0);
            short h1 = f2bf(r1); float r2 = r1 - bf2f(h1);
            wB[4][0][i] = h0; wB[4][1][i] = h1; wB[4][2][i] = f2bf(r2);
        }
    }

    // ---- LSNN state (C-layout: row = rt*16 + q*4 + r, col = hcol) ----
    f32x4 v[2], cu[2], ba[2];
    #pragma unroll
    for (int rt = 0; rt < 2; ++rt) {
        v[rt]  = (f32x4){0.f,0.f,0.f,0.f};
        cu[rt] = (f32x4){0.f,0.f,0.f,0.f};
        ba[rt] = (f32x4){0.f,0.f,0.f,0.f};
    }

    // ---- encoder (tid<256): row = tid>>3, ch = tid&7 ----
    float ve = 0.f, ce = 0.f;
    if (tid < 256) {
        float xv = 50.f * x[(bbase + (tid >> 3)) * 4 + (tid & 3)];
        ce = ((tid & 7) < 4) ? fmaxf(xv, 0.f) : fmaxf(-xv, 0.f);
    }

    const float KA = 1.4285714285714286e-06f;  // DT * (1/700)
    const float KB = 2.5714285714285714e-03f;  // (1/700) * 1.8

    // zero zbuf (both parities; cols >=136 stay 0 forever)
    for (int idx = tid; idx < 2 * BT * ZSTR; idx += 512) ((short*)zbuf)[idx] = 0;
    __syncthreads();

    // prologue: x_0 spikes -> zbuf[0]; dm(t=0) -> registers
    if (tid < 256) {
        float vv = ve + 0.1f * (ce - ve);
        float sp = (vv - 1.0f > 0.f) ? 1.f : 0.f;
        ve = (1.f - sp) * vv;
        zbuf[0][tid >> 3][128 + (tid & 7)] = (sp > 0.5f) ? (short)0x3F80 : (short)0;
    }
    float mr[2][4];
    {
        const float* dmt = dm + (size_t)bbase * HDIM;
        #pragma unroll
        for (int rt = 0; rt < 2; ++rt)
            #pragma unroll
            for (int r = 0; r < 4; ++r)
                mr[rt][r] = dmt[(rt * 16 + q * 4 + r) * HDIM + hcol];
    }

    for (int t = 0; t < TSTEPS; ++t) {
        const int p = t & 1;
        __syncthreads();   // zbuf[p] (z_{t-1}, x_t) ready; zbuf[1-p] free

        // 1) dm prefetch for t+1 -> registers (full step to cover HBM latency)
        float mrn[2][4];
        {
            int tn = (t + 1 < TSTEPS) ? t + 1 : TSTEPS - 1;
            const float* dmn = dm + ((size_t)tn * BTOT + bbase) * HDIM;
            #pragma unroll
            for (int rt = 0; rt < 2; ++rt)
                #pragma unroll
                for (int r = 0; r < 4; ++r)
                    mrn[rt][r] = dmn[(rt * 16 + q * 4 + r) * HDIM + hcol];
        }

        // 2) encoder spike for t+1 -> zbuf[1-p] cols 128..135
        if (tid < 256) {
            float vv = ve + 0.1f * (ce - ve);
            float sp = (vv - 1.0f > 0.f) ? 1.f : 0.f;
            ve = (1.f - sp) * vv;
            zbuf[1 - p][tid >> 3][128 + (tid & 7)] = (sp > 0.5f) ? (short)0x3F80 : (short)0;
        }

        // 3) MFMA: acc[rt] = [z_{t-1} | x_t] @ [w_rec | w_in]^T  (K = 160)
        f32x4 acc[2];
        #pragma unroll
        for (int rt = 0; rt < 2; ++rt) {
            f32x4 a = {0.f, 0.f, 0.f, 0.f};
            #pragma unroll
            for (int kt = 0; kt < 5; ++kt) {
                bf16x8 zA = *reinterpret_cast<const bf16x8*>(&zbuf[p][rt * 16 + li][kt * 32 + q * 8]);
                #pragma unroll
                for (int pp = 0; pp < 3; ++pp)
                    a = __builtin_amdgcn_mfma_f32_16x16x32_bf16(zA, wB[kt][pp], a, 0, 0, 0);
            }
            acc[rt] = a;
        }

        // 4) cell update + z publish + spike&keep bitmask (NO cross-lane reduce)
        #pragma unroll
        for (int rt = 0; rt < 2; ++rt) {
            #pragma unroll
            for (int r = 0; r < 4; ++r) {
                const int row = rt * 16 + q * 4 + r;
                float vd = v[rt][r] + 0.1f * (cu[rt][r] - v[rt][r]);
                float id = cu[rt][r] - 0.2f * cu[rt][r];
                float bd = ba[rt][r] + KA * (1.0f - ba[rt][r]);
                float z  = (vd - bd > 0.f) ? 1.f : 0.f;
                v[rt][r]  = (1.f - z) * vd;
                ba[rt][r] = bd + z * KB;
                cu[rt][r] = id + acc[rt][r];
                zbuf[1 - p][row][hcol] = (z > 0.5f) ? (short)0x3F80 : (short)0;
                unsigned long long bm = __ballot((z > 0.5f) && (mr[rt][r] > 1.0f));
                if (li == 0)
                    maskb[t][row][wv] = (unsigned short)(bm >> (q * 16));
            }
        }
        #pragma unroll
        for (int rt = 0; rt < 2; ++rt)
            #pragma unroll
            for (int r = 0; r < 4; ++r) mr[rt][r] = mrn[rt][r];
    }

    __syncthreads();   // maskb complete
    asm volatile("" ::: "memory");  // keep w_out loads below the step loop

    // ---- batched readout: s[t][row][o] = (z&keep)*2 @ w_out^T via MFMA ----
    bf16x8 woB[4][2];   // B[k][j] = w_out[j][k], j = li (cols 0,1 valid), 2-way split
    #pragma unroll
    for (int kt = 0; kt < 4; ++kt) {
        #pragma unroll
        for (int i = 0; i < 8; ++i) {
            float w0 = 0.f;
            if (li < 2) w0 = w_out[li * HDIM + kt * 32 + q * 8 + i];
            short h0 = f2bf(w0);
            woB[kt][0][i] = h0;
            woB[kt][1][i] = f2bf(w0 - bf2f(h0));
        }
    }
    for (int T = wv; T < TSTEPS * 2; T += NWAVE) {
        const int t  = T >> 1;
        const int rt = T & 1;
        f32x4 ac = {0.f, 0.f, 0.f, 0.f};
        #pragma unroll
        for (int kt = 0; kt < 4; ++kt) {
            unsigned b = (unsigned)maskb[t][rt * 16 + li][2 * kt + (q >> 1)];
            b = (b >> ((q & 1) * 8)) & 0xffu;
            // expand 8 bits -> 8 bf16 values {0, 2.0} (2.0 = 0x4000)
            u32x4 aw;
            aw.x = ((b & 1u)   << 14) | ((b & 2u)   << 29);
            aw.y = ((b & 4u)   << 12) | ((b & 8u)   << 27);
            aw.z = ((b & 16u)  << 10) | ((b & 32u)  << 25);
            aw.w = ((b & 64u)  <<  8) | ((b & 128u) << 23);
            bf16x8 A = __builtin_bit_cast(bf16x8, aw);
            ac = __builtin_amdgcn_mfma_f32_16x16x32_bf16(A, woB[kt][0], ac, 0, 0, 0);
            ac = __builtin_amdgcn_mfma_f32_16x16x32_bf16(A, woB[kt][1], ac, 0, 0, 0);
        }
        if (li < 2) {
            #pragma unroll
            for (int r = 0; r < 4; ++r)
                sbuf[t][rt * 16 + q * 4 + r][li] = ac[r];
        }
    }
    __syncthreads();   // sbuf complete

    // ---- LI recurrence + max + softmax (wave 0: lane l = (row=l>>1, o=l&1)) ----
    if (wv == 0) {
        const int row = l >> 1, o = l & 1;
        float vo = 0.f, io = 0.f, mx = 0.f;
        for (int t = 0; t < TSTEPS; ++t) {
            float s = sbuf[t][row][o];
            float von = vo + 0.1f * (io - vo);
            io = io - 0.2f * io + s;
            vo = von;
            mx = fmaxf(mx, vo);
        }
        float other = __shfl_xor(mx, 1);
        float mmax  = fmaxf(mx, other);
        float e  = expf(mx - mmax);
        float eo = expf(other - mmax);
        out[(size_t)(bbase + row) * 2 + o] = e / (e + eo);
    }
}

extern "C" void kernel_launch(void* const* d_in, const int* in_sizes, int n_in,
                              void* d_out, int out_size, void* d_ws, size_t ws_size,
                              hipStream_t stream) {
    const float* x     = (const float*)d_in[0];
    const float* w_in  = (const float*)d_in[1];
    const float* w_rec = (const float*)d_in[2];
    const float* w_out = (const float*)d_in[3];
    const float* dmask = (const float*)d_in[4];
    float* outp = (float*)d_out;

    lsnn7<<<BTOT / BT, 512, 0, stream>>>(x, w_in, w_rec, w_out, dmask, outp);
}